// Round 2
// baseline (1511.285 us; speedup 1.0000x reference)
//
#include <hip/hip_runtime.h>

// Problem constants (from reference)
#define Nn 50000
#define Ee 600000
#define Rr 4
#define BN_EPS 1e-5f

typedef __bf16 bfrag  __attribute__((ext_vector_type(8)));
typedef float  f32x4  __attribute__((ext_vector_type(4)));

// ---- scatter-add over all relations: agg[r][dst][f] += x[src][f] ----
__global__ __launch_bounds__(256) void scatter_all_k(
    const float* __restrict__ x, const int* __restrict__ ei,
    const int* __restrict__ et, float* __restrict__ agg)
{
    int tid = blockIdx.x * 256 + threadIdx.x;
    int e = tid >> 5;
    if (e >= Ee) return;
    int f4 = (tid & 31) << 2;
    int r   = et[e];
    int dst = ei[e];        // edge_index[0] = row (destination)
    int src = ei[Ee + e];   // edge_index[1] = col (source)
    float4 xv = *(const float4*)(x + (size_t)src * 128 + f4);
    float* p = agg + ((size_t)r * Nn + dst) * 128 + f4;
    atomicAdd(p + 0, xv.x); atomicAdd(p + 1, xv.y);
    atomicAdd(p + 2, xv.z); atomicAdd(p + 3, xv.w);
}

// ---- scatter-add filtered to one relation (small-ws path) ----
__global__ __launch_bounds__(256) void scatter_rel_k(
    const float* __restrict__ x, const int* __restrict__ ei,
    const int* __restrict__ et, float* __restrict__ aggr, int rel)
{
    int tid = blockIdx.x * 256 + threadIdx.x;
    int e = tid >> 5;
    if (e >= Ee) return;
    if (et[e] != rel) return;
    int f4 = (tid & 31) << 2;
    int dst = ei[e];
    int src = ei[Ee + e];
    float4 xv = *(const float4*)(x + (size_t)src * 128 + f4);
    float* p = aggr + (size_t)dst * 128 + f4;
    atomicAdd(p + 0, xv.x); atomicAdd(p + 1, xv.y);
    atomicAdd(p + 2, xv.z); atomicAdd(p + 3, xv.w);
}

// ---- h1 = (x + agg_r) @ W1_r + b1_r (in place, fp32), BN sum/sumsq per feature ----
__global__ __launch_bounds__(256) void gemm1_bn_k(
    const float* __restrict__ x,
    float* __restrict__ h,                 // (N,128): in=agg_r, out=h1_r
    const float* __restrict__ W1r,         // (128,128) [k][n]
    const float* __restrict__ b1r,         // (128)
    float* __restrict__ gsum, float* __restrict__ gsq)
{
    const int n0 = blockIdx.x * 64;
    const int t  = threadIdx.x;

    __shared__ __attribute__((aligned(16))) __bf16 As[64][136];
    __shared__ __attribute__((aligned(16))) __bf16 Ws[128][136];
    __shared__ float s_sum[128], s_sq[128];

    if (t < 128) { s_sum[t] = 0.f; s_sq[t] = 0.f; }

    // Stage W transposed: Ws[n][k] = W1r[k][n]
    for (int i = t; i < 4096; i += 256) {
        float4 wv = ((const float4*)W1r)[i];
        int j = i << 2;
        int k = j >> 7, n = j & 127;
        Ws[n + 0][k] = (__bf16)wv.x; Ws[n + 1][k] = (__bf16)wv.y;
        Ws[n + 2][k] = (__bf16)wv.z; Ws[n + 3][k] = (__bf16)wv.w;
    }
    // Stage A = x + agg (bf16), zero-pad rows >= N
    for (int i = t; i < 2048; i += 256) {
        int m = i >> 5, kq = (i & 31) << 2;
        int gm = n0 + m;
        float v0 = 0.f, v1 = 0.f, v2 = 0.f, v3 = 0.f;
        if (gm < Nn) {
            float4 av = *(const float4*)(h + (size_t)gm * 128 + kq);
            float4 xv = *(const float4*)(x + (size_t)gm * 128 + kq);
            v0 = av.x + xv.x; v1 = av.y + xv.y; v2 = av.z + xv.z; v3 = av.w + xv.w;
        }
        As[m][kq + 0] = (__bf16)v0; As[m][kq + 1] = (__bf16)v1;
        As[m][kq + 2] = (__bf16)v2; As[m][kq + 3] = (__bf16)v3;
    }
    __syncthreads();

    const int w = t >> 6, l = t & 63, ln = l & 15, quad = l >> 4;
    f32x4 acc[8];
#pragma unroll
    for (int c = 0; c < 8; ++c) acc[c] = (f32x4){0.f, 0.f, 0.f, 0.f};

#pragma unroll
    for (int kk = 0; kk < 4; ++kk) {
        int ks = kk * 32 + quad * 8;
        bfrag a = *(const bfrag*)&As[w * 16 + ln][ks];
#pragma unroll
        for (int c = 0; c < 8; ++c) {
            bfrag b = *(const bfrag*)&Ws[c * 16 + ln][ks];
            acc[c] = __builtin_amdgcn_mfma_f32_16x16x32_bf16(a, b, acc[c], 0, 0, 0);
        }
    }

    // Epilogue: add bias, store fp32 in place, accumulate BN stats
#pragma unroll
    for (int c = 0; c < 8; ++c) {
        int col = c * 16 + ln;
        float bias = b1r[col];
        float ps = 0.f, pq = 0.f;
#pragma unroll
        for (int reg = 0; reg < 4; ++reg) {
            int gm = n0 + w * 16 + quad * 4 + reg;
            float v = acc[c][reg] + bias;
            if (gm < Nn) {
                h[(size_t)gm * 128 + col] = v;
                ps += v; pq += v * v;
            }
        }
        ps += __shfl_xor(ps, 16); pq += __shfl_xor(pq, 16);
        ps += __shfl_xor(ps, 32); pq += __shfl_xor(pq, 32);
        if (quad == 0) { atomicAdd(&s_sum[col], ps); atomicAdd(&s_sq[col], pq); }
    }
    __syncthreads();
    if (t < 128) {
        atomicAdd(&gsum[t], s_sum[t]);
        atomicAdd(&gsq[t],  s_sq[t]);
    }
}

// ---- BN coefs: a = gamma*rsqrt(var+eps), c = beta - mean*a ----
__global__ void finalize_k(
    const float* __restrict__ gsum, const float* __restrict__ gsq,
    const float* __restrict__ gamma, const float* __restrict__ beta,
    float* __restrict__ coefA, float* __restrict__ coefC)
{
    int i = threadIdx.x;   // 128
    float mean = gsum[i] * (1.0f / Nn);
    float var  = gsq[i] * (1.0f / Nn) - mean * mean;
    float a    = gamma[i] * rsqrtf(fmaxf(var, 0.f) + BN_EPS);
    coefA[i] = a;
    coefC[i] = beta[i] - mean * a;
}

// ---- out = x @ W_self + b_self (initializes out) ----
__global__ __launch_bounds__(256) void gemm_self_k(
    const float* __restrict__ x, const float* __restrict__ Wself,
    const float* __restrict__ bself, float* __restrict__ out)
{
    const int n0 = blockIdx.x * 64;
    const int t  = threadIdx.x;
    __shared__ __attribute__((aligned(16))) __bf16 As[64][136];
    __shared__ __attribute__((aligned(16))) __bf16 Ws[128][136];

    for (int i = t; i < 4096; i += 256) {
        float4 wv = ((const float4*)Wself)[i];
        int j = i << 2;
        int k = j >> 7, n = j & 127;
        Ws[n + 0][k] = (__bf16)wv.x; Ws[n + 1][k] = (__bf16)wv.y;
        Ws[n + 2][k] = (__bf16)wv.z; Ws[n + 3][k] = (__bf16)wv.w;
    }
    for (int i = t; i < 2048; i += 256) {
        int m = i >> 5, kq = (i & 31) << 2;
        int gm = n0 + m;
        float v0 = 0.f, v1 = 0.f, v2 = 0.f, v3 = 0.f;
        if (gm < Nn) {
            float4 xv = *(const float4*)(x + (size_t)gm * 128 + kq);
            v0 = xv.x; v1 = xv.y; v2 = xv.z; v3 = xv.w;
        }
        As[m][kq + 0] = (__bf16)v0; As[m][kq + 1] = (__bf16)v1;
        As[m][kq + 2] = (__bf16)v2; As[m][kq + 3] = (__bf16)v3;
    }
    __syncthreads();

    const int w = t >> 6, l = t & 63, ln = l & 15, quad = l >> 4;
    f32x4 acc[8];
#pragma unroll
    for (int c = 0; c < 8; ++c) acc[c] = (f32x4){0.f, 0.f, 0.f, 0.f};
#pragma unroll
    for (int kk = 0; kk < 4; ++kk) {
        int ks = kk * 32 + quad * 8;
        bfrag a = *(const bfrag*)&As[w * 16 + ln][ks];
#pragma unroll
        for (int c = 0; c < 8; ++c) {
            bfrag b = *(const bfrag*)&Ws[c * 16 + ln][ks];
            acc[c] = __builtin_amdgcn_mfma_f32_16x16x32_bf16(a, b, acc[c], 0, 0, 0);
        }
    }
#pragma unroll
    for (int c = 0; c < 8; ++c) {
        int col = c * 16 + ln;
        float bias = bself[col];
#pragma unroll
        for (int reg = 0; reg < 4; ++reg) {
            int gm = n0 + w * 16 + quad * 4 + reg;
            if (gm < Nn) out[(size_t)gm * 128 + col] = acc[c][reg] + bias;
        }
    }
}

// ---- out += relu(a*h1+c) @ W2_r + b2_r ----
__global__ __launch_bounds__(256) void gemm2_acc_k(
    const float* __restrict__ h,            // (N,128) fp32
    const float* __restrict__ W2r,          // (128,128)
    const float* __restrict__ coefA, const float* __restrict__ coefC,
    const float* __restrict__ b2r,
    float* __restrict__ out)
{
    const int n0 = blockIdx.x * 64;
    const int t  = threadIdx.x;
    __shared__ __attribute__((aligned(16))) __bf16 As[64][136];
    __shared__ __attribute__((aligned(16))) __bf16 Ws[128][136];

    for (int i = t; i < 4096; i += 256) {
        float4 wv = ((const float4*)W2r)[i];
        int j = i << 2;
        int k = j >> 7, n = j & 127;
        Ws[n + 0][k] = (__bf16)wv.x; Ws[n + 1][k] = (__bf16)wv.y;
        Ws[n + 2][k] = (__bf16)wv.z; Ws[n + 3][k] = (__bf16)wv.w;
    }
    for (int i = t; i < 2048; i += 256) {
        int m = i >> 5, kq = (i & 31) << 2;
        int gm = n0 + m;
        float v0 = 0.f, v1 = 0.f, v2 = 0.f, v3 = 0.f;
        if (gm < Nn) {
            float4 hv = *(const float4*)(h + (size_t)gm * 128 + kq);
            v0 = fmaxf(coefA[kq + 0] * hv.x + coefC[kq + 0], 0.f);
            v1 = fmaxf(coefA[kq + 1] * hv.y + coefC[kq + 1], 0.f);
            v2 = fmaxf(coefA[kq + 2] * hv.z + coefC[kq + 2], 0.f);
            v3 = fmaxf(coefA[kq + 3] * hv.w + coefC[kq + 3], 0.f);
        }
        As[m][kq + 0] = (__bf16)v0; As[m][kq + 1] = (__bf16)v1;
        As[m][kq + 2] = (__bf16)v2; As[m][kq + 3] = (__bf16)v3;
    }
    __syncthreads();

    const int w = t >> 6, l = t & 63, ln = l & 15, quad = l >> 4;
    f32x4 acc[8];
#pragma unroll
    for (int c = 0; c < 8; ++c) acc[c] = (f32x4){0.f, 0.f, 0.f, 0.f};
#pragma unroll
    for (int kk = 0; kk < 4; ++kk) {
        int ks = kk * 32 + quad * 8;
        bfrag a = *(const bfrag*)&As[w * 16 + ln][ks];
#pragma unroll
        for (int c = 0; c < 8; ++c) {
            bfrag b = *(const bfrag*)&Ws[c * 16 + ln][ks];
            acc[c] = __builtin_amdgcn_mfma_f32_16x16x32_bf16(a, b, acc[c], 0, 0, 0);
        }
    }
#pragma unroll
    for (int c = 0; c < 8; ++c) {
        int col = c * 16 + ln;
        float bias = b2r[col];
#pragma unroll
        for (int reg = 0; reg < 4; ++reg) {
            int gm = n0 + w * 16 + quad * 4 + reg;
            if (gm < Nn) out[(size_t)gm * 128 + col] += acc[c][reg] + bias;
        }
    }
}

extern "C" void kernel_launch(void* const* d_in, const int* in_sizes, int n_in,
                              void* d_out, int out_size, void* d_ws, size_t ws_size,
                              hipStream_t stream) {
    const float* x     = (const float*)d_in[0];
    const int*   ei    = (const int*)d_in[1];
    const int*   et    = (const int*)d_in[2];
    const float* Wself = (const float*)d_in[3];
    const float* bself = (const float*)d_in[4];
    const float* W1    = (const float*)d_in[5];
    const float* b1    = (const float*)d_in[6];
    const float* gamma = (const float*)d_in[7];
    const float* beta  = (const float*)d_in[8];
    const float* W2    = (const float*)d_in[9];
    const float* b2    = (const float*)d_in[10];
    float* out = (float*)d_out;

    char* ws = (char*)d_ws;
    // ws layout: gsum[512] | gsq[512] | coefA[512] | coefC[512] | agg...
    float* gsum  = (float*)ws;
    float* gsq   = (float*)(ws + 2048);
    float* coefA = (float*)(ws + 4096);
    float* coefC = (float*)(ws + 6144);
    float* agg   = (float*)(ws + 8192);
    const size_t REL  = (size_t)Nn * 128;      // elements per relation buffer
    const size_t RELB = REL * sizeof(float);   // 25,600,000 bytes

    const int GEMM_BLOCKS = (Nn + 63) / 64;    // 782
    const int SCAT_BLOCKS = (Ee * 32) / 256;   // 75,000

    if (ws_size >= 8192 + 4 * RELB) {
        // Big path: all relations resident
        hipMemsetAsync(ws, 0, 8192 + 4 * RELB, stream);
        scatter_all_k<<<SCAT_BLOCKS, 256, 0, stream>>>(x, ei, et, agg);
        gemm_self_k<<<GEMM_BLOCKS, 256, 0, stream>>>(x, Wself, bself, out);
        for (int r = 0; r < 4; ++r) {
            float* hr = agg + (size_t)r * REL;
            gemm1_bn_k<<<GEMM_BLOCKS, 256, 0, stream>>>(
                x, hr, W1 + r * 16384, b1 + r * 128, gsum + r * 128, gsq + r * 128);
            finalize_k<<<1, 128, 0, stream>>>(
                gsum + r * 128, gsq + r * 128, gamma + r * 128, beta + r * 128,
                coefA + r * 128, coefC + r * 128);
            gemm2_acc_k<<<GEMM_BLOCKS, 256, 0, stream>>>(
                hr, W2 + r * 16384, coefA + r * 128, coefC + r * 128,
                b2 + r * 128, out);
        }
    } else {
        // Small path: one relation buffer, relation-filtered scatter
        hipMemsetAsync(ws, 0, 8192, stream);
        gemm_self_k<<<GEMM_BLOCKS, 256, 0, stream>>>(x, Wself, bself, out);
        for (int r = 0; r < 4; ++r) {
            hipMemsetAsync(agg, 0, RELB, stream);
            scatter_rel_k<<<SCAT_BLOCKS, 256, 0, stream>>>(x, ei, et, agg, r);
            gemm1_bn_k<<<GEMM_BLOCKS, 256, 0, stream>>>(
                x, agg, W1 + r * 16384, b1 + r * 128, gsum + r * 128, gsq + r * 128);
            finalize_k<<<1, 128, 0, stream>>>(
                gsum + r * 128, gsq + r * 128, gamma + r * 128, beta + r * 128,
                coefA + r * 128, coefC + r * 128);
            gemm2_acc_k<<<GEMM_BLOCKS, 256, 0, stream>>>(
                agg, W2 + r * 16384, coefA + r * 128, coefC + r * 128,
                b2 + r * 128, out);
        }
    }
}

// Round 3
// 460.884 us; speedup vs baseline: 3.2791x; 3.2791x over previous
//
#include <hip/hip_runtime.h>

// Problem constants (from reference)
#define Nn 50000
#define Ee 600000
#define Rr 4
#define NSEG (Rr * Nn)          // 200,000 segments
#define NBIN 200704             // 196 * 1024, padded for int4 scan
#define BN_EPS 1e-5f

typedef __bf16 bfrag  __attribute__((ext_vector_type(8)));
typedef float  f32x4  __attribute__((ext_vector_type(4)));

__device__ __forceinline__ unsigned short f2b(float f) {
    union { float f; unsigned int u; } v; v.f = f;
    return (unsigned short)((v.u + 0x7FFFu + ((v.u >> 16) & 1u)) >> 16);
}
__device__ __forceinline__ float b2f(unsigned short u) {
    union { unsigned int u; float f; } v; v.u = ((unsigned int)u) << 16; return v.f;
}

// ---- 1. histogram over (relation, dst) bins ----
__global__ __launch_bounds__(256) void hist_k(
    const int* __restrict__ ei, const int* __restrict__ et, int* __restrict__ hist)
{
    int e = blockIdx.x * 256 + threadIdx.x;
    if (e >= Ee) return;
    atomicAdd(&hist[et[e] * Nn + ei[e]], 1);
}

// ---- 2a. block-local exclusive scan (1024 bins/block) ----
__global__ __launch_bounds__(256) void scan1_k(
    const int* __restrict__ hist, int* __restrict__ offs, int* __restrict__ bsum)
{
    int t = threadIdx.x, b = blockIdx.x;
    int base = b * 1024 + t * 4;
    int4 c = *(const int4*)(hist + base);
    int s = c.x + c.y + c.z + c.w;
    __shared__ int tmp[256];
    tmp[t] = s; __syncthreads();
    for (int off = 1; off < 256; off <<= 1) {
        int v = (t >= off) ? tmp[t - off] : 0;
        __syncthreads(); tmp[t] += v; __syncthreads();
    }
    int excl = tmp[t] - s;
    int4 o; o.x = excl; o.y = excl + c.x; o.z = o.y + c.y; o.w = o.z + c.z;
    *(int4*)(offs + base) = o;
    if (t == 255) bsum[b] = tmp[255];
}

// ---- 2b. scan of 196 block sums ----
__global__ void scan2_k(const int* __restrict__ bsum, int* __restrict__ bscan)
{
    int t = threadIdx.x;  // 256
    int s = (t < 196) ? bsum[t] : 0;
    __shared__ int tmp[256];
    tmp[t] = s; __syncthreads();
    for (int off = 1; off < 256; off <<= 1) {
        int v = (t >= off) ? tmp[t - off] : 0;
        __syncthreads(); tmp[t] += v; __syncthreads();
    }
    bscan[t] = tmp[t] - s;
}

// ---- 2c. add block bases; also init cursor copy ----
__global__ __launch_bounds__(256) void scan3_k(
    int* __restrict__ offs, int* __restrict__ cur, const int* __restrict__ bscan)
{
    int t = threadIdx.x, b = blockIdx.x;
    int add = bscan[b];
    int base = b * 1024 + t * 4;
    int4 o = *(int4*)(offs + base);
    o.x += add; o.y += add; o.z += add; o.w += add;
    *(int4*)(offs + base) = o;
    *(int4*)(cur + base) = o;
}

// ---- 3. bucket fill: sorted_src[pos] = source node ----
__global__ __launch_bounds__(256) void fill_k(
    const int* __restrict__ ei, const int* __restrict__ et,
    int* __restrict__ cur, int* __restrict__ ssrc)
{
    int e = blockIdx.x * 256 + threadIdx.x;
    if (e >= Ee) return;
    int bin = et[e] * Nn + ei[e];
    int pos = atomicAdd(&cur[bin], 1);
    ssrc[pos] = ei[Ee + e];
}

// ---- 4. segmented gather-sum: h0[r][dst] = x[dst] + sum_{src in seg} x[src], bf16 out ----
__global__ __launch_bounds__(256) void agg_k(
    const float* __restrict__ x, const int* __restrict__ offs,
    const int* __restrict__ ssrc, unsigned short* __restrict__ h)
{
    int seg = blockIdx.x * 4 + (threadIdx.x >> 6);   // 4 waves/block
    if (seg >= NSEG) return;
    int lane = threadIdx.x & 63;
    int dst = seg % Nn;                              // seg = r*Nn + dst
    float2 acc = *((const float2*)(x + (size_t)dst * 128) + lane);
    int beg = offs[seg], end = offs[seg + 1];
    for (int e = beg; e < end; ++e) {
        int s = ssrc[e];
        float2 v = *((const float2*)(x + (size_t)s * 128) + lane);
        acc.x += v.x; acc.y += v.y;
    }
    unsigned int p = ((unsigned int)f2b(acc.y) << 16) | f2b(acc.x);
    ((unsigned int*)h)[(size_t)seg * 64 + lane] = p;
}

// ---- 5. h1_r = h0_r @ W1_r + b1_r (bf16 in place), BN sum/sumsq (fp32-exact) ----
__global__ __launch_bounds__(256) void gemm1_bn_k(
    unsigned short* __restrict__ h,          // (R,N,128) bf16, in/out
    const float* __restrict__ W1,            // (R,128,128) [k][n]
    const float* __restrict__ b1,            // (R,128)
    float* __restrict__ gsum, float* __restrict__ gsq)
{
    const int r  = blockIdx.y;
    const int n0 = blockIdx.x * 64;
    const int t  = threadIdx.x;
    unsigned short* hr = h + (size_t)r * Nn * 128;

    __shared__ __attribute__((aligned(16))) __bf16 As[64][136];
    __shared__ __attribute__((aligned(16))) __bf16 Ws[128][136];
    __shared__ float s_sum[128], s_sq[128];

    if (t < 128) { s_sum[t] = 0.f; s_sq[t] = 0.f; }

    // Stage W transposed: Ws[n][k] = W1[r][k][n] (fp32 -> bf16)
    {
        const float* Wr = W1 + r * 16384;
        for (int i = t; i < 4096; i += 256) {
            float4 wv = ((const float4*)Wr)[i];
            int j = i << 2, k = j >> 7, n = j & 127;
            Ws[n + 0][k] = (__bf16)wv.x; Ws[n + 1][k] = (__bf16)wv.y;
            Ws[n + 2][k] = (__bf16)wv.z; Ws[n + 3][k] = (__bf16)wv.w;
        }
    }
    // Stage A: copy bf16 rows (16B chunks), zero-pad rows >= N
    for (int i = t; i < 1024; i += 256) {
        int m = i >> 4, kc = (i & 15) << 3;
        int gm = n0 + m;
        uint4 v = make_uint4(0, 0, 0, 0);
        if (gm < Nn) v = *(const uint4*)(hr + (size_t)gm * 128 + kc);
        *(uint4*)&As[m][kc] = v;
    }
    __syncthreads();

    const int w = t >> 6, l = t & 63, ln = l & 15, quad = l >> 4;
    f32x4 acc[8];
#pragma unroll
    for (int c = 0; c < 8; ++c) acc[c] = (f32x4){0.f, 0.f, 0.f, 0.f};
#pragma unroll
    for (int kk = 0; kk < 4; ++kk) {
        int ks = kk * 32 + quad * 8;
        bfrag a = *(const bfrag*)&As[w * 16 + ln][ks];
#pragma unroll
        for (int c = 0; c < 8; ++c) {
            bfrag b = *(const bfrag*)&Ws[c * 16 + ln][ks];
            acc[c] = __builtin_amdgcn_mfma_f32_16x16x32_bf16(a, b, acc[c], 0, 0, 0);
        }
    }

    // Epilogue: +bias, BN stats from fp32 acc, store bf16 in place
#pragma unroll
    for (int c = 0; c < 8; ++c) {
        int col = c * 16 + ln;
        float bias = b1[r * 128 + col];
        float ps = 0.f, pq = 0.f;
#pragma unroll
        for (int reg = 0; reg < 4; ++reg) {
            int gm = n0 + w * 16 + quad * 4 + reg;
            float v = acc[c][reg] + bias;
            if (gm < Nn) {
                hr[(size_t)gm * 128 + col] = f2b(v);
                ps += v; pq += v * v;
            }
        }
        ps += __shfl_xor(ps, 16); pq += __shfl_xor(pq, 16);
        ps += __shfl_xor(ps, 32); pq += __shfl_xor(pq, 32);
        if (quad == 0) { atomicAdd(&s_sum[col], ps); atomicAdd(&s_sq[col], pq); }
    }
    __syncthreads();
    if (t < 128) {
        atomicAdd(&gsum[r * 128 + t], s_sum[t]);
        atomicAdd(&gsq[r * 128 + t],  s_sq[t]);
    }
}

// ---- 6. BN coefs for all relations ----
__global__ void finalize_k(
    const float* __restrict__ gsum, const float* __restrict__ gsq,
    const float* __restrict__ gamma, const float* __restrict__ beta,
    float* __restrict__ coefA, float* __restrict__ coefC)
{
    int i = threadIdx.x;   // 512
    float mean = gsum[i] * (1.0f / Nn);
    float var  = gsq[i] * (1.0f / Nn) - mean * mean;
    float a    = gamma[i] * rsqrtf(fmaxf(var, 0.f) + BN_EPS);
    coefA[i] = a;
    coefC[i] = beta[i] - mean * a;
}

// ---- 7. out = x@W_self + sum_r relu(a*h1+c)@W2_r + biases, single pass ----
__global__ __launch_bounds__(256) void gemm2_out_k(
    const float* __restrict__ x,
    const unsigned short* __restrict__ h,     // (R,N,128) bf16
    const float* __restrict__ Wself, const float* __restrict__ bself,
    const float* __restrict__ W2, const float* __restrict__ b2,
    const float* __restrict__ coefA, const float* __restrict__ coefC,
    float* __restrict__ out)
{
    const int n0 = blockIdx.x * 64;
    const int t  = threadIdx.x;
    __shared__ __attribute__((aligned(16))) __bf16 As[64][136];
    __shared__ __attribute__((aligned(16))) __bf16 Ws[128][136];

    const int w = t >> 6, l = t & 63, ln = l & 15, quad = l >> 4;
    f32x4 acc[8];
#pragma unroll
    for (int c = 0; c < 8; ++c) acc[c] = (f32x4){0.f, 0.f, 0.f, 0.f};

    for (int rr = 0; rr < 5; ++rr) {
        const float* Wsrc = (rr < 4) ? (W2 + rr * 16384) : Wself;
        for (int i = t; i < 4096; i += 256) {
            float4 wv = ((const float4*)Wsrc)[i];
            int j = i << 2, k = j >> 7, n = j & 127;
            Ws[n + 0][k] = (__bf16)wv.x; Ws[n + 1][k] = (__bf16)wv.y;
            Ws[n + 2][k] = (__bf16)wv.z; Ws[n + 3][k] = (__bf16)wv.w;
        }
        if (rr < 4) {
            const unsigned short* hr = h + (size_t)rr * Nn * 128;
            const float* cA = coefA + rr * 128;
            const float* cC = coefC + rr * 128;
            for (int i = t; i < 2048; i += 256) {     // uint2 = 4 bf16
                int m = i >> 5, kq = (i & 31) << 2;
                int gm = n0 + m;
                float v0 = 0.f, v1 = 0.f, v2 = 0.f, v3 = 0.f;
                if (gm < Nn) {
                    uint2 hv = *(const uint2*)(hr + (size_t)gm * 128 + kq);
                    v0 = fmaxf(cA[kq + 0] * b2f(hv.x & 0xFFFF)  + cC[kq + 0], 0.f);
                    v1 = fmaxf(cA[kq + 1] * b2f(hv.x >> 16)     + cC[kq + 1], 0.f);
                    v2 = fmaxf(cA[kq + 2] * b2f(hv.y & 0xFFFF)  + cC[kq + 2], 0.f);
                    v3 = fmaxf(cA[kq + 3] * b2f(hv.y >> 16)     + cC[kq + 3], 0.f);
                }
                As[m][kq + 0] = (__bf16)v0; As[m][kq + 1] = (__bf16)v1;
                As[m][kq + 2] = (__bf16)v2; As[m][kq + 3] = (__bf16)v3;
            }
        } else {
            for (int i = t; i < 2048; i += 256) {
                int m = i >> 5, kq = (i & 31) << 2;
                int gm = n0 + m;
                float v0 = 0.f, v1 = 0.f, v2 = 0.f, v3 = 0.f;
                if (gm < Nn) {
                    float4 xv = *(const float4*)(x + (size_t)gm * 128 + kq);
                    v0 = xv.x; v1 = xv.y; v2 = xv.z; v3 = xv.w;
                }
                As[m][kq + 0] = (__bf16)v0; As[m][kq + 1] = (__bf16)v1;
                As[m][kq + 2] = (__bf16)v2; As[m][kq + 3] = (__bf16)v3;
            }
        }
        __syncthreads();
#pragma unroll
        for (int kk = 0; kk < 4; ++kk) {
            int ks = kk * 32 + quad * 8;
            bfrag a = *(const bfrag*)&As[w * 16 + ln][ks];
#pragma unroll
            for (int c = 0; c < 8; ++c) {
                bfrag b = *(const bfrag*)&Ws[c * 16 + ln][ks];
                acc[c] = __builtin_amdgcn_mfma_f32_16x16x32_bf16(a, b, acc[c], 0, 0, 0);
            }
        }
        __syncthreads();
    }

    // Epilogue: fused total bias, single fp32 store
#pragma unroll
    for (int c = 0; c < 8; ++c) {
        int col = c * 16 + ln;
        float bias = bself[col] + b2[col] + b2[128 + col] + b2[256 + col] + b2[384 + col];
#pragma unroll
        for (int reg = 0; reg < 4; ++reg) {
            int gm = n0 + w * 16 + quad * 4 + reg;
            if (gm < Nn) out[(size_t)gm * 128 + col] = acc[c][reg] + bias;
        }
    }
}

extern "C" void kernel_launch(void* const* d_in, const int* in_sizes, int n_in,
                              void* d_out, int out_size, void* d_ws, size_t ws_size,
                              hipStream_t stream) {
    const float* x     = (const float*)d_in[0];
    const int*   ei    = (const int*)d_in[1];
    const int*   et    = (const int*)d_in[2];
    const float* Wself = (const float*)d_in[3];
    const float* bself = (const float*)d_in[4];
    const float* W1    = (const float*)d_in[5];
    const float* b1    = (const float*)d_in[6];
    const float* gamma = (const float*)d_in[7];
    const float* beta  = (const float*)d_in[8];
    const float* W2    = (const float*)d_in[9];
    const float* b2    = (const float*)d_in[10];
    float* out = (float*)d_out;

    char* ws = (char*)d_ws;
    // ws layout (bytes):
    int*   hist  = (int*)(ws + 0);                    // NBIN*4 = 802,816
    float* gsum  = (float*)(ws + 802816);             // 2048
    float* gsq   = (float*)(ws + 804864);             // 2048
    float* coefA = (float*)(ws + 806912);             // 2048
    float* coefC = (float*)(ws + 808960);             // 2048
    int*   bsum  = (int*)(ws + 811008);               // 1024
    int*   bscan = (int*)(ws + 812032);               // 1024
    int*   offs  = (int*)(ws + 813056);               // 802,816
    int*   cur   = (int*)(ws + 1615872);              // 802,816
    int*   ssrc  = (int*)(ws + 2418688);              // 2,400,000
    unsigned short* h = (unsigned short*)(ws + 4818688); // 51,200,000  (total ~56 MB)

    // zero hist + gsum + gsq (contiguous)
    hipMemsetAsync(ws, 0, 802816 + 4096, stream);

    const int EB = (Ee + 255) / 256;   // 2344
    hist_k <<<EB, 256, 0, stream>>>(ei, et, hist);
    scan1_k<<<196, 256, 0, stream>>>(hist, offs, bsum);
    scan2_k<<<1, 256, 0, stream>>>(bsum, bscan);
    scan3_k<<<196, 256, 0, stream>>>(offs, cur, bscan);
    fill_k <<<EB, 256, 0, stream>>>(ei, et, cur, ssrc);

    agg_k<<<NSEG / 4, 256, 0, stream>>>(x, offs, ssrc, h);

    dim3 g1((Nn + 63) / 64, Rr);
    gemm1_bn_k<<<g1, 256, 0, stream>>>(h, W1, b1, gsum, gsq);
    finalize_k<<<1, 512, 0, stream>>>(gsum, gsq, gamma, beta, coefA, coefC);
    gemm2_out_k<<<(Nn + 63) / 64, 256, 0, stream>>>(
        x, h, Wself, bself, W2, b2, coefA, coefC, out);
}

// Round 6
// 391.577 us; speedup vs baseline: 3.8595x; 1.1770x over previous
//
#include <hip/hip_runtime.h>

// Problem constants (from reference)
#define Nn 50000
#define Ee 600000
#define Rr 4
#define NSEG (Rr * Nn)          // 200,000 segments
#define NBIN 200704             // 196 * 1024, padded for int4 scan
#define BN_EPS 1e-5f

typedef __bf16 bfrag  __attribute__((ext_vector_type(8)));
typedef float  f32x4  __attribute__((ext_vector_type(4)));

__device__ __forceinline__ unsigned short f2b(float f) {
    union { float f; unsigned int u; } v; v.f = f;
    return (unsigned short)((v.u + 0x7FFFu + ((v.u >> 16) & 1u)) >> 16);
}
__device__ __forceinline__ float b2f(unsigned short u) {
    union { unsigned int u; float f; } v; v.u = ((unsigned int)u) << 16; return v.f;
}

// ---- 0a. transpose all weights to bf16: WT[mat][n][k] = W[mat][k][n]
//      mats 0..3 = W1_r, 4..7 = W2_r, 8 = Wself ----
__global__ __launch_bounds__(256) void wt_k(
    const float* __restrict__ W1, const float* __restrict__ W2,
    const float* __restrict__ Wself, unsigned short* __restrict__ WT)
{
    int idx = blockIdx.x * 256 + threadIdx.x;       // < 9*16384
    int mat = idx >> 14;
    int rem = idx & 16383;
    int n = rem >> 7, k = rem & 127;
    const float* src = (mat < 4) ? (W1 + mat * 16384)
                     : (mat < 8) ? (W2 + (mat - 4) * 16384) : Wself;
    WT[idx] = f2b(src[k * 128 + n]);
}

// ---- 0b. x -> bf16 packed (xb: 2 bf16 per uint, 64 uints per row) ----
__global__ __launch_bounds__(256) void xbf_k(
    const float* __restrict__ x, unsigned int* __restrict__ xb)
{
    int i = blockIdx.x * 256 + threadIdx.x;         // < 3,200,000
    if (i >= (Nn * 64)) return;
    float2 v = ((const float2*)x)[i];
    xb[i] = ((unsigned int)f2b(v.y) << 16) | f2b(v.x);
}

// ---- 1. histogram over (relation, dst) bins ----
__global__ __launch_bounds__(256) void hist_k(
    const int* __restrict__ ei, const int* __restrict__ et, int* __restrict__ hist)
{
    int e = blockIdx.x * 256 + threadIdx.x;
    if (e >= Ee) return;
    atomicAdd(&hist[et[e] * Nn + ei[e]], 1);
}

// ---- 2a. block-local exclusive scan (1024 bins/block) ----
__global__ __launch_bounds__(256) void scan1_k(
    const int* __restrict__ hist, int* __restrict__ offs, int* __restrict__ bsum)
{
    int t = threadIdx.x, b = blockIdx.x;
    int base = b * 1024 + t * 4;
    int4 c = *(const int4*)(hist + base);
    int s = c.x + c.y + c.z + c.w;
    __shared__ int tmp[256];
    tmp[t] = s; __syncthreads();
    for (int off = 1; off < 256; off <<= 1) {
        int v = (t >= off) ? tmp[t - off] : 0;
        __syncthreads(); tmp[t] += v; __syncthreads();
    }
    int excl = tmp[t] - s;
    int4 o; o.x = excl; o.y = excl + c.x; o.z = o.y + c.y; o.w = o.z + c.z;
    *(int4*)(offs + base) = o;
    if (t == 255) bsum[b] = tmp[255];
}

// ---- 2b. scan of 196 block sums ----
__global__ void scan2_k(const int* __restrict__ bsum, int* __restrict__ bscan)
{
    int t = threadIdx.x;  // 256
    int s = (t < 196) ? bsum[t] : 0;
    __shared__ int tmp[256];
    tmp[t] = s; __syncthreads();
    for (int off = 1; off < 256; off <<= 1) {
        int v = (t >= off) ? tmp[t - off] : 0;
        __syncthreads(); tmp[t] += v; __syncthreads();
    }
    bscan[t] = tmp[t] - s;
}

// ---- 2c. add block bases; init cursor copy ----
__global__ __launch_bounds__(256) void scan3_k(
    int* __restrict__ offs, int* __restrict__ cur, const int* __restrict__ bscan)
{
    int t = threadIdx.x, b = blockIdx.x;
    int add = bscan[b];
    int base = b * 1024 + t * 4;
    int4 o = *(int4*)(offs + base);
    o.x += add; o.y += add; o.z += add; o.w += add;
    *(int4*)(offs + base) = o;
    *(int4*)(cur + base) = o;
}

// ---- 3. bucket fill: sorted_src[pos] = source node ----
__global__ __launch_bounds__(256) void fill_k(
    const int* __restrict__ ei, const int* __restrict__ et,
    int* __restrict__ cur, int* __restrict__ ssrc)
{
    int e = blockIdx.x * 256 + threadIdx.x;
    if (e >= Ee) return;
    int bin = et[e] * Nn + ei[e];
    int pos = atomicAdd(&cur[bin], 1);
    ssrc[pos] = ei[Ee + e];
}

// ---- 4. segmented gather-sum over bf16 x: h0[seg] = xb[dst] + sum xb[src] ----
__global__ __launch_bounds__(256) void agg_k(
    const unsigned int* __restrict__ xb, const int* __restrict__ offs,
    const int* __restrict__ ssrc, unsigned int* __restrict__ h)
{
    int seg = blockIdx.x * 4 + (threadIdx.x >> 6);   // 4 waves/block
    if (seg >= NSEG) return;
    int lane = threadIdx.x & 63;
    int r = seg / Nn;
    int dst = seg - r * Nn;
    unsigned int p = xb[(size_t)dst * 64 + lane];
    float a0 = b2f((unsigned short)(p & 0xFFFF));
    float a1 = b2f((unsigned short)(p >> 16));
    int beg = offs[seg], end = offs[seg + 1];
    for (int e = beg; e < end; ++e) {
        unsigned int v = xb[(size_t)ssrc[e] * 64 + lane];
        a0 += b2f((unsigned short)(v & 0xFFFF));
        a1 += b2f((unsigned short)(v >> 16));
    }
    h[(size_t)seg * 64 + lane] = ((unsigned int)f2b(a1) << 16) | f2b(a0);
}

// ---- 5. h1_r = h0_r @ W1_r + b1_r (bf16 in place), BN sum/sumsq (fp32) ----
__global__ __launch_bounds__(256) void gemm1_bn_k(
    unsigned short* __restrict__ h,            // (R,N,128) bf16, in/out
    const unsigned short* __restrict__ WT,     // bf16 [9][128][128], n-major
    const float* __restrict__ b1,
    float* __restrict__ gsum, float* __restrict__ gsq)
{
    const int r  = blockIdx.y;
    const int n0 = blockIdx.x * 64;
    const int t  = threadIdx.x;
    unsigned short* hr = h + (size_t)r * Nn * 128;

    __shared__ __attribute__((aligned(16))) __bf16 As[64][136];
    __shared__ __attribute__((aligned(16))) __bf16 Ws[128][136];
    __shared__ float s_sum[128], s_sq[128];

    if (t < 128) { s_sum[t] = 0.f; s_sq[t] = 0.f; }

    // Stage W: contiguous uint4 (8 shorts) copies, 2048 chunks total
    {
        const unsigned short* Wr = WT + r * 16384;
        for (int i = t; i < 2048; i += 256) {
            int n = i >> 4, kc = (i & 15) << 3;          // kc in shorts
            uint4 v = *(const uint4*)(Wr + n * 128 + kc);
            *(uint4*)&Ws[n][kc] = v;
        }
    }
    // Stage A: copy bf16 rows (8-short chunks), zero-pad rows >= N
    for (int i = t; i < 1024; i += 256) {
        int m = i >> 4, kc = (i & 15) << 3;
        int gm = n0 + m;
        uint4 v = make_uint4(0, 0, 0, 0);
        if (gm < Nn) v = *(const uint4*)(hr + (size_t)gm * 128 + kc);
        *(uint4*)&As[m][kc] = v;
    }
    __syncthreads();

    const int w = t >> 6, l = t & 63, ln = l & 15, quad = l >> 4;
    f32x4 acc[8];
#pragma unroll
    for (int c = 0; c < 8; ++c) acc[c] = (f32x4){0.f, 0.f, 0.f, 0.f};
#pragma unroll
    for (int kk = 0; kk < 4; ++kk) {
        int ks = kk * 32 + quad * 8;
        bfrag a = *(const bfrag*)&As[w * 16 + ln][ks];
#pragma unroll
        for (int c = 0; c < 8; ++c) {
            bfrag b = *(const bfrag*)&Ws[c * 16 + ln][ks];
            acc[c] = __builtin_amdgcn_mfma_f32_16x16x32_bf16(a, b, acc[c], 0, 0, 0);
        }
    }

    // Epilogue: +bias, BN stats from fp32 acc, store bf16 in place
#pragma unroll
    for (int c = 0; c < 8; ++c) {
        int col = c * 16 + ln;
        float bias = b1[r * 128 + col];
        float ps = 0.f, pq = 0.f;
#pragma unroll
        for (int reg = 0; reg < 4; ++reg) {
            int gm = n0 + w * 16 + quad * 4 + reg;
            float v = acc[c][reg] + bias;
            if (gm < Nn) {
                hr[(size_t)gm * 128 + col] = f2b(v);
                ps += v; pq += v * v;
            }
        }
        ps += __shfl_xor(ps, 16); pq += __shfl_xor(pq, 16);
        ps += __shfl_xor(ps, 32); pq += __shfl_xor(pq, 32);
        if (quad == 0) { atomicAdd(&s_sum[col], ps); atomicAdd(&s_sq[col], pq); }
    }
    __syncthreads();
    if (t < 128) {
        atomicAdd(&gsum[r * 128 + t], s_sum[t]);
        atomicAdd(&gsq[r * 128 + t],  s_sq[t]);
    }
}

// ---- 6. BN coefs ----
__global__ void finalize_k(
    const float* __restrict__ gsum, const float* __restrict__ gsq,
    const float* __restrict__ gamma, const float* __restrict__ beta,
    float* __restrict__ coefA, float* __restrict__ coefC)
{
    int i = threadIdx.x;   // 512
    float mean = gsum[i] * (1.0f / Nn);
    float var  = gsq[i] * (1.0f / Nn) - mean * mean;
    float a    = gamma[i] * rsqrtf(fmaxf(var, 0.f) + BN_EPS);
    coefA[i] = a;
    coefC[i] = beta[i] - mean * a;
}

// ---- 7. out = x@W_self + sum_r relu(a*h1+c)@W2_r + biases ----
__global__ __launch_bounds__(256) void gemm2_out_k(
    const unsigned int* __restrict__ xb,
    const unsigned short* __restrict__ h,       // (R,N,128) bf16
    const unsigned short* __restrict__ WT,      // bf16 [9][128][128]
    const float* __restrict__ bself, const float* __restrict__ b2,
    const float* __restrict__ coefA, const float* __restrict__ coefC,
    float* __restrict__ out)
{
    const int n0 = blockIdx.x * 64;
    const int t  = threadIdx.x;
    __shared__ __attribute__((aligned(16))) __bf16 As[64][136];
    __shared__ __attribute__((aligned(16))) __bf16 Ws[128][136];

    const int w = t >> 6, l = t & 63, ln = l & 15, quad = l >> 4;
    f32x4 acc[8];
#pragma unroll
    for (int c = 0; c < 8; ++c) acc[c] = (f32x4){0.f, 0.f, 0.f, 0.f};

    for (int rr = 0; rr < 5; ++rr) {
        // Stage W from WT (mats 4..7 = W2_r, 8 = Wself), 2048 uint4 chunks
        const unsigned short* Wr = WT + (rr < 4 ? (4 + rr) : 8) * 16384;
        for (int i = t; i < 2048; i += 256) {
            int n = i >> 4, kc = (i & 15) << 3;
            uint4 v = *(const uint4*)(Wr + n * 128 + kc);
            *(uint4*)&Ws[n][kc] = v;
        }
        if (rr < 4) {
            const unsigned short* hrp = h + (size_t)rr * Nn * 128;
            const float* cA = coefA + rr * 128;
            const float* cC = coefC + rr * 128;
            for (int i = t; i < 2048; i += 256) {     // 4 bf16 per item
                int m = i >> 5, kq = (i & 31) << 2;
                int gm = n0 + m;
                float v0 = 0.f, v1 = 0.f, v2 = 0.f, v3 = 0.f;
                if (gm < Nn) {
                    uint2 hv = *(const uint2*)(hrp + (size_t)gm * 128 + kq);
                    v0 = fmaxf(cA[kq + 0] * b2f((unsigned short)(hv.x & 0xFFFF)) + cC[kq + 0], 0.f);
                    v1 = fmaxf(cA[kq + 1] * b2f((unsigned short)(hv.x >> 16))    + cC[kq + 1], 0.f);
                    v2 = fmaxf(cA[kq + 2] * b2f((unsigned short)(hv.y & 0xFFFF)) + cC[kq + 2], 0.f);
                    v3 = fmaxf(cA[kq + 3] * b2f((unsigned short)(hv.y >> 16))    + cC[kq + 3], 0.f);
                }
                unsigned int p0 = ((unsigned int)f2b(v1) << 16) | f2b(v0);
                unsigned int p1 = ((unsigned int)f2b(v3) << 16) | f2b(v2);
                *(uint2*)&As[m][kq] = make_uint2(p0, p1);   // b64 write
            }
        } else {
            for (int i = t; i < 1024; i += 256) {     // uint4 = 8 bf16 copy
                int m = i >> 4, kc = (i & 15) << 3;
                int gm = n0 + m;
                uint4 v = make_uint4(0, 0, 0, 0);
                if (gm < Nn) v = *(const uint4*)(xb + (size_t)gm * 64 + (kc >> 1));
                *(uint4*)&As[m][kc] = v;
            }
        }
        __syncthreads();
#pragma unroll
        for (int kk = 0; kk < 4; ++kk) {
            int ks = kk * 32 + quad * 8;
            bfrag a = *(const bfrag*)&As[w * 16 + ln][ks];
#pragma unroll
            for (int c = 0; c < 8; ++c) {
                bfrag b = *(const bfrag*)&Ws[c * 16 + ln][ks];
                acc[c] = __builtin_amdgcn_mfma_f32_16x16x32_bf16(a, b, acc[c], 0, 0, 0);
            }
        }
        __syncthreads();
    }

    // Epilogue: fused total bias, single fp32 store
#pragma unroll
    for (int c = 0; c < 8; ++c) {
        int col = c * 16 + ln;
        float bias = bself[col] + b2[col] + b2[128 + col] + b2[256 + col] + b2[384 + col];
#pragma unroll
        for (int reg = 0; reg < 4; ++reg) {
            int gm = n0 + w * 16 + quad * 4 + reg;
            if (gm < Nn) out[(size_t)gm * 128 + col] = acc[c][reg] + bias;
        }
    }
}

extern "C" void kernel_launch(void* const* d_in, const int* in_sizes, int n_in,
                              void* d_out, int out_size, void* d_ws, size_t ws_size,
                              hipStream_t stream) {
    const float* x     = (const float*)d_in[0];
    const int*   ei    = (const int*)d_in[1];
    const int*   et    = (const int*)d_in[2];
    const float* Wself = (const float*)d_in[3];
    const float* bself = (const float*)d_in[4];
    const float* W1    = (const float*)d_in[5];
    const float* b1    = (const float*)d_in[6];
    const float* gamma = (const float*)d_in[7];
    const float* beta  = (const float*)d_in[8];
    const float* W2    = (const float*)d_in[9];
    const float* b2    = (const float*)d_in[10];
    float* out = (float*)d_out;

    char* ws = (char*)d_ws;
    // ws layout (bytes):
    int*   hist  = (int*)(ws + 0);                      // 802,816
    float* gsum  = (float*)(ws + 802816);               // 2048
    float* gsq   = (float*)(ws + 804864);               // 2048
    float* coefA = (float*)(ws + 806912);               // 2048
    float* coefC = (float*)(ws + 808960);               // 2048
    int*   bsum  = (int*)(ws + 811008);                 // 1024
    int*   bscan = (int*)(ws + 812032);                 // 1024
    int*   offs  = (int*)(ws + 813056);                 // 802,816
    int*   cur   = (int*)(ws + 1615872);                // 802,816
    int*   ssrc  = (int*)(ws + 2418688);                // 2,400,000
    unsigned short* h  = (unsigned short*)(ws + 4818688);   // 51,200,000
    unsigned int*   xb = (unsigned int*)(ws + 56018688);    // 12,800,000
    unsigned short* WT = (unsigned short*)(ws + 68818688);  // 294,912 -> total ~69.1 MB

    (void)hipMemsetAsync(ws, 0, 806912, stream);   // hist + gsum + gsq

    const int EB = (Ee + 255) / 256;         // 2344
    wt_k  <<<(9 * 16384) / 256, 256, 0, stream>>>(W1, W2, Wself, WT);
    xbf_k <<<(Nn * 64 + 255) / 256, 256, 0, stream>>>(x, xb);
    hist_k <<<EB, 256, 0, stream>>>(ei, et, hist);
    scan1_k<<<196, 256, 0, stream>>>(hist, offs, bsum);
    scan2_k<<<1, 256, 0, stream>>>(bsum, bscan);
    scan3_k<<<196, 256, 0, stream>>>(offs, cur, bscan);
    fill_k <<<EB, 256, 0, stream>>>(ei, et, cur, ssrc);

    agg_k<<<NSEG / 4, 256, 0, stream>>>(xb, offs, ssrc, (unsigned int*)h);

    dim3 g1((Nn + 63) / 64, Rr);
    gemm1_bn_k<<<g1, 256, 0, stream>>>(h, WT, b1, gsum, gsq);
    finalize_k<<<1, 512, 0, stream>>>(gsum, gsq, gamma, beta, coefA, coefC);
    gemm2_out_k<<<(Nn + 63) / 64, 256, 0, stream>>>(
        xb, h, WT, bself, b2, coefA, coefC, out);
}

// Round 7
// 300.415 us; speedup vs baseline: 5.0307x; 1.3035x over previous
//
#include <hip/hip_runtime.h>

#define Nn 50000
#define Ee 600000
#define Rr 4
#define NSEG (Rr * Nn)
#define NBIN 200704             // 196*1024, padded for int4 scan
#define BN_EPS 1e-5f

typedef __bf16 bfrag  __attribute__((ext_vector_type(8)));
typedef float  f32x4  __attribute__((ext_vector_type(4)));

__device__ __forceinline__ unsigned short f2b(float f) {
    union { float f; unsigned int u; } v; v.f = f;
    return (unsigned short)((v.u + 0x7FFFu + ((v.u >> 16) & 1u)) >> 16);
}
__device__ __forceinline__ float b2f(unsigned short u) {
    union { unsigned int u; float f; } v; v.u = ((unsigned int)u) << 16; return v.f;
}

// ---- 0a. transpose all weights to bf16: WT[mat][n][k]; 0..3=W1, 4..7=W2, 8=Wself
__global__ __launch_bounds__(256) void wt_k(
    const float* __restrict__ W1, const float* __restrict__ W2,
    const float* __restrict__ Wself, unsigned short* __restrict__ WT)
{
    int idx = blockIdx.x * 256 + threadIdx.x;       // < 9*16384
    int mat = idx >> 14;
    int rem = idx & 16383;
    int n = rem >> 7, k = rem & 127;
    const float* src = (mat < 4) ? (W1 + mat * 16384)
                     : (mat < 8) ? (W2 + (mat - 4) * 16384) : Wself;
    WT[idx] = f2b(src[k * 128 + n]);
}

// ---- 0b. x -> packed bf16 (2 per uint, 64 uints/row) ----
__global__ __launch_bounds__(256) void xbf_k(
    const float* __restrict__ x, unsigned int* __restrict__ xb)
{
    int i = blockIdx.x * 256 + threadIdx.x;
    if (i >= (Nn * 64)) return;
    float2 v = ((const float2*)x)[i];
    xb[i] = ((unsigned int)f2b(v.y) << 16) | f2b(v.x);
}

// ---- 1. histogram over (relation, dst) bins ----
__global__ __launch_bounds__(256) void hist_k(
    const int* __restrict__ ei, const int* __restrict__ et, int* __restrict__ hist)
{
    int e = blockIdx.x * 256 + threadIdx.x;
    if (e >= Ee) return;
    atomicAdd(&hist[et[e] * Nn + ei[e]], 1);
}

// ---- 2a/b/c. exclusive scan over NBIN ----
__global__ __launch_bounds__(256) void scan1_k(
    const int* __restrict__ hist, int* __restrict__ offs, int* __restrict__ bsum)
{
    int t = threadIdx.x, b = blockIdx.x;
    int base = b * 1024 + t * 4;
    int4 c = *(const int4*)(hist + base);
    int s = c.x + c.y + c.z + c.w;
    __shared__ int tmp[256];
    tmp[t] = s; __syncthreads();
    for (int off = 1; off < 256; off <<= 1) {
        int v = (t >= off) ? tmp[t - off] : 0;
        __syncthreads(); tmp[t] += v; __syncthreads();
    }
    int excl = tmp[t] - s;
    int4 o; o.x = excl; o.y = excl + c.x; o.z = o.y + c.y; o.w = o.z + c.z;
    *(int4*)(offs + base) = o;
    if (t == 255) bsum[b] = tmp[255];
}
__global__ void scan2_k(const int* __restrict__ bsum, int* __restrict__ bscan)
{
    int t = threadIdx.x;
    int s = (t < 196) ? bsum[t] : 0;
    __shared__ int tmp[256];
    tmp[t] = s; __syncthreads();
    for (int off = 1; off < 256; off <<= 1) {
        int v = (t >= off) ? tmp[t - off] : 0;
        __syncthreads(); tmp[t] += v; __syncthreads();
    }
    bscan[t] = tmp[t] - s;
}
__global__ __launch_bounds__(256) void scan3_k(
    int* __restrict__ offs, int* __restrict__ cur, const int* __restrict__ bscan)
{
    int t = threadIdx.x, b = blockIdx.x;
    int add = bscan[b];
    int base = b * 1024 + t * 4;
    int4 o = *(int4*)(offs + base);
    o.x += add; o.y += add; o.z += add; o.w += add;
    *(int4*)(offs + base) = o;
    *(int4*)(cur + base) = o;
}

// ---- 3. bucket fill ----
__global__ __launch_bounds__(256) void fill_k(
    const int* __restrict__ ei, const int* __restrict__ et,
    int* __restrict__ cur, int* __restrict__ ssrc)
{
    int e = blockIdx.x * 256 + threadIdx.x;
    if (e >= Ee) return;
    int bin = et[e] * Nn + ei[e];
    int pos = atomicAdd(&cur[bin], 1);
    ssrc[pos] = ei[Ee + e];
}

// ---- 4. FUSED: gather-agg (CSR) -> h0 tile in LDS -> @W1_r + b1 -> h1 (bf16) + BN stats
//      128-row tiles, grid (391, 4) ----
__global__ __launch_bounds__(256) void gemm1f_k(
    const unsigned int* __restrict__ xb, const int* __restrict__ offs,
    const int* __restrict__ ssrc, const unsigned short* __restrict__ WT,
    const float* __restrict__ b1, unsigned short* __restrict__ h,
    float* __restrict__ gsum, float* __restrict__ gsq)
{
    const int r  = blockIdx.y;
    const int n0 = blockIdx.x * 128;
    const int t  = threadIdx.x;

    __shared__ __attribute__((aligned(16))) __bf16 As[128][136];
    __shared__ __attribute__((aligned(16))) __bf16 Ws[128][136];
    __shared__ float s_sum[128], s_sq[128];
    if (t < 128) { s_sum[t] = 0.f; s_sq[t] = 0.f; }

    // Stage W1_r (2048 uint4 chunks)
    {
        const unsigned short* Wr = WT + r * 16384;
        for (int i = t; i < 2048; i += 256) {
            int n = i >> 4, kc = (i & 15) << 3;
            *(uint4*)&Ws[n][kc] = *(const uint4*)(Wr + n * 128 + kc);
        }
    }
    // Gather h0 = x[dst] + sum x[src] into As. 2 passes x 64 rows; 4 thr/row x 16 uints.
    for (int pass = 0; pass < 2; ++pass) {
        int row = pass * 64 + (t >> 2);
        int q   = t & 3;
        int gm  = n0 + row;
        float acc[32];
        if (gm < Nn) {
            const uint4* xr = (const uint4*)(xb + (size_t)gm * 64 + q * 16);
            uint4 u0 = xr[0], u1 = xr[1], u2 = xr[2], u3 = xr[3];
            unsigned int us[16] = {u0.x,u0.y,u0.z,u0.w, u1.x,u1.y,u1.z,u1.w,
                                   u2.x,u2.y,u2.z,u2.w, u3.x,u3.y,u3.z,u3.w};
#pragma unroll
            for (int j = 0; j < 16; ++j) {
                acc[2*j]   = b2f((unsigned short)(us[j] & 0xFFFF));
                acc[2*j+1] = b2f((unsigned short)(us[j] >> 16));
            }
            int seg = r * Nn + gm;
            int beg = offs[seg], end = offs[seg + 1];
            for (int e = beg; e < end; ++e) {
                const uint4* sr = (const uint4*)(xb + (size_t)ssrc[e] * 64 + q * 16);
                uint4 v0 = sr[0], v1 = sr[1], v2 = sr[2], v3 = sr[3];
                unsigned int vs[16] = {v0.x,v0.y,v0.z,v0.w, v1.x,v1.y,v1.z,v1.w,
                                       v2.x,v2.y,v2.z,v2.w, v3.x,v3.y,v3.z,v3.w};
#pragma unroll
                for (int j = 0; j < 16; ++j) {
                    acc[2*j]   += b2f((unsigned short)(vs[j] & 0xFFFF));
                    acc[2*j+1] += b2f((unsigned short)(vs[j] >> 16));
                }
            }
        } else {
#pragma unroll
            for (int j = 0; j < 32; ++j) acc[j] = 0.f;
        }
        unsigned int pk[16];
#pragma unroll
        for (int j = 0; j < 16; ++j)
            pk[j] = ((unsigned int)f2b(acc[2*j+1]) << 16) | f2b(acc[2*j]);
        uint4* dst = (uint4*)&As[row][q * 32];
        dst[0] = make_uint4(pk[0],  pk[1],  pk[2],  pk[3]);
        dst[1] = make_uint4(pk[4],  pk[5],  pk[6],  pk[7]);
        dst[2] = make_uint4(pk[8],  pk[9],  pk[10], pk[11]);
        dst[3] = make_uint4(pk[12], pk[13], pk[14], pk[15]);
    }
    __syncthreads();

    // MFMA: wave w handles rows w*32..w*32+31 (2 m-frags)
    const int w = t >> 6, l = t & 63, ln = l & 15, quad = l >> 4;
    f32x4 acc2[2][8];
#pragma unroll
    for (int mf = 0; mf < 2; ++mf)
#pragma unroll
        for (int c = 0; c < 8; ++c) acc2[mf][c] = (f32x4){0.f,0.f,0.f,0.f};
#pragma unroll
    for (int kk = 0; kk < 4; ++kk) {
        int ks = kk * 32 + quad * 8;
        bfrag a0 = *(const bfrag*)&As[w * 32 + ln][ks];
        bfrag a1 = *(const bfrag*)&As[w * 32 + 16 + ln][ks];
#pragma unroll
        for (int c = 0; c < 8; ++c) {
            bfrag b = *(const bfrag*)&Ws[c * 16 + ln][ks];
            acc2[0][c] = __builtin_amdgcn_mfma_f32_16x16x32_bf16(a0, b, acc2[0][c], 0, 0, 0);
            acc2[1][c] = __builtin_amdgcn_mfma_f32_16x16x32_bf16(a1, b, acc2[1][c], 0, 0, 0);
        }
    }
    __syncthreads();   // all As reads done before epilogue overwrites

    // Epilogue: +bias, BN stats (fp32), write bf16 back to As
#pragma unroll
    for (int c = 0; c < 8; ++c) {
        int col = c * 16 + ln;
        float bias = b1[r * 128 + col];
        float ps = 0.f, pq = 0.f;
#pragma unroll
        for (int mf = 0; mf < 2; ++mf)
#pragma unroll
            for (int reg = 0; reg < 4; ++reg) {
                int lrow = w * 32 + mf * 16 + quad * 4 + reg;
                float v = acc2[mf][c][reg] + bias;
                As[lrow][col] = (__bf16)v;
                if (n0 + lrow < Nn) { ps += v; pq += v * v; }
            }
        ps += __shfl_xor(ps, 16); pq += __shfl_xor(pq, 16);
        ps += __shfl_xor(ps, 32); pq += __shfl_xor(pq, 32);
        if (quad == 0) { atomicAdd(&s_sum[col], ps); atomicAdd(&s_sq[col], pq); }
    }
    __syncthreads();

    // Coalesced h1 store from As
    unsigned short* hr = h + (size_t)r * Nn * 128;
    for (int i = t; i < 2048; i += 256) {
        int m = i >> 4, kc = (i & 15) << 3;
        int gm = n0 + m;
        if (gm < Nn) *(uint4*)(hr + (size_t)gm * 128 + kc) = *(const uint4*)&As[m][kc];
    }
    if (t < 128) {
        atomicAdd(&gsum[r * 128 + t], s_sum[t]);
        atomicAdd(&gsq[r * 128 + t],  s_sq[t]);
    }
}

// ---- 6. BN coefs ----
__global__ void finalize_k(
    const float* __restrict__ gsum, const float* __restrict__ gsq,
    const float* __restrict__ gamma, const float* __restrict__ beta,
    float* __restrict__ coefA, float* __restrict__ coefC)
{
    int i = threadIdx.x;   // 512
    float mean = gsum[i] * (1.0f / Nn);
    float var  = gsq[i] * (1.0f / Nn) - mean * mean;
    float a    = gamma[i] * rsqrtf(fmaxf(var, 0.f) + BN_EPS);
    coefA[i] = a;
    coefC[i] = beta[i] - mean * a;
}

// ---- 7. out = x@W_self + sum_r relu(a*h1+c)@W2_r + biases; 128-row tiles ----
__global__ __launch_bounds__(256) void gemm2f_k(
    const unsigned int* __restrict__ xb,
    const unsigned short* __restrict__ h,
    const unsigned short* __restrict__ WT,
    const float* __restrict__ bself, const float* __restrict__ b2,
    const float* __restrict__ coefA, const float* __restrict__ coefC,
    float* __restrict__ out)
{
    const int n0 = blockIdx.x * 128;
    const int t  = threadIdx.x;
    __shared__ __attribute__((aligned(16))) __bf16 As[128][136];
    __shared__ __attribute__((aligned(16))) __bf16 Ws[128][136];

    const int w = t >> 6, l = t & 63, ln = l & 15, quad = l >> 4;
    f32x4 acc2[2][8];
#pragma unroll
    for (int mf = 0; mf < 2; ++mf)
#pragma unroll
        for (int c = 0; c < 8; ++c) acc2[mf][c] = (f32x4){0.f,0.f,0.f,0.f};

    for (int rr = 0; rr < 5; ++rr) {
        const unsigned short* Wr = WT + (rr < 4 ? (4 + rr) : 8) * 16384;
        for (int i = t; i < 2048; i += 256) {
            int n = i >> 4, kc = (i & 15) << 3;
            *(uint4*)&Ws[n][kc] = *(const uint4*)(Wr + n * 128 + kc);
        }
        if (rr < 4) {
            const unsigned short* hrp = h + (size_t)rr * Nn * 128;
            const float* cA = coefA + rr * 128;
            const float* cC = coefC + rr * 128;
            for (int i = t; i < 4096; i += 256) {     // 128 rows x 32 chunks of 4
                int m = i >> 5, kq = (i & 31) << 2;
                int gm = n0 + m;
                float v0 = 0.f, v1 = 0.f, v2 = 0.f, v3 = 0.f;
                if (gm < Nn) {
                    uint2 hv = *(const uint2*)(hrp + (size_t)gm * 128 + kq);
                    v0 = fmaxf(cA[kq + 0] * b2f((unsigned short)(hv.x & 0xFFFF)) + cC[kq + 0], 0.f);
                    v1 = fmaxf(cA[kq + 1] * b2f((unsigned short)(hv.x >> 16))    + cC[kq + 1], 0.f);
                    v2 = fmaxf(cA[kq + 2] * b2f((unsigned short)(hv.y & 0xFFFF)) + cC[kq + 2], 0.f);
                    v3 = fmaxf(cA[kq + 3] * b2f((unsigned short)(hv.y >> 16))    + cC[kq + 3], 0.f);
                }
                unsigned int p0 = ((unsigned int)f2b(v1) << 16) | f2b(v0);
                unsigned int p1 = ((unsigned int)f2b(v3) << 16) | f2b(v2);
                *(uint2*)&As[m][kq] = make_uint2(p0, p1);
            }
        } else {
            for (int i = t; i < 2048; i += 256) {
                int m = i >> 4, kc = (i & 15) << 3;
                int gm = n0 + m;
                uint4 v = make_uint4(0, 0, 0, 0);
                if (gm < Nn) v = *(const uint4*)(xb + (size_t)gm * 64 + (kc >> 1));
                *(uint4*)&As[m][kc] = v;
            }
        }
        __syncthreads();
#pragma unroll
        for (int kk = 0; kk < 4; ++kk) {
            int ks = kk * 32 + quad * 8;
            bfrag a0 = *(const bfrag*)&As[w * 32 + ln][ks];
            bfrag a1 = *(const bfrag*)&As[w * 32 + 16 + ln][ks];
#pragma unroll
            for (int c = 0; c < 8; ++c) {
                bfrag b = *(const bfrag*)&Ws[c * 16 + ln][ks];
                acc2[0][c] = __builtin_amdgcn_mfma_f32_16x16x32_bf16(a0, b, acc2[0][c], 0, 0, 0);
                acc2[1][c] = __builtin_amdgcn_mfma_f32_16x16x32_bf16(a1, b, acc2[1][c], 0, 0, 0);
            }
        }
        __syncthreads();
    }

    // Epilogue: 2 passes of 64 rows through Ws as fp32 [64][132], coalesced stores
    float bias[8];
#pragma unroll
    for (int c = 0; c < 8; ++c) {
        int col = c * 16 + ln;
        bias[c] = bself[col] + b2[col] + b2[128 + col] + b2[256 + col] + b2[384 + col];
    }
    float* fws = (float*)Ws;
    for (int p = 0; p < 2; ++p) {
        if ((w >> 1) == p) {
#pragma unroll
            for (int mf = 0; mf < 2; ++mf)
#pragma unroll
                for (int c = 0; c < 8; ++c) {
                    int lrow = (w & 1) * 32 + mf * 16 + quad * 4;
                    int col  = c * 16 + ln;
#pragma unroll
                    for (int reg = 0; reg < 4; ++reg)
                        fws[(lrow + reg) * 132 + col] = acc2[mf][c][reg] + bias[c];
                }
        }
        __syncthreads();
        for (int i = t; i < 2048; i += 256) {      // 64 rows x 32 float4
            int m = i >> 5, kc = (i & 31) << 2;
            int gm = n0 + p * 64 + m;
            if (gm < Nn)
                *(float4*)(out + (size_t)gm * 128 + kc) = *(const float4*)&fws[m * 132 + kc];
        }
        __syncthreads();
    }
}

extern "C" void kernel_launch(void* const* d_in, const int* in_sizes, int n_in,
                              void* d_out, int out_size, void* d_ws, size_t ws_size,
                              hipStream_t stream) {
    const float* x     = (const float*)d_in[0];
    const int*   ei    = (const int*)d_in[1];
    const int*   et    = (const int*)d_in[2];
    const float* Wself = (const float*)d_in[3];
    const float* bself = (const float*)d_in[4];
    const float* W1    = (const float*)d_in[5];
    const float* b1    = (const float*)d_in[6];
    const float* gamma = (const float*)d_in[7];
    const float* beta  = (const float*)d_in[8];
    const float* W2    = (const float*)d_in[9];
    const float* b2    = (const float*)d_in[10];
    float* out = (float*)d_out;

    char* ws = (char*)d_ws;
    int*   hist  = (int*)(ws + 0);                      // 802,816
    float* gsum  = (float*)(ws + 802816);               // 2048
    float* gsq   = (float*)(ws + 804864);               // 2048
    float* coefA = (float*)(ws + 806912);               // 2048
    float* coefC = (float*)(ws + 808960);               // 2048
    int*   bsum  = (int*)(ws + 811008);                 // 1024
    int*   bscan = (int*)(ws + 812032);                 // 1024
    int*   offs  = (int*)(ws + 813056);                 // 802,816
    int*   cur   = (int*)(ws + 1615872);                // 802,816
    int*   ssrc  = (int*)(ws + 2418688);                // 2,400,000
    unsigned short* h  = (unsigned short*)(ws + 4818688);   // 51,200,000 (h1 only)
    unsigned int*   xb = (unsigned int*)(ws + 56018688);    // 12,800,000
    unsigned short* WT = (unsigned short*)(ws + 68818688);  // 294,912

    (void)hipMemsetAsync(ws, 0, 806912, stream);   // hist + gsum + gsq

    const int EB = (Ee + 255) / 256;
    wt_k  <<<(9 * 16384) / 256, 256, 0, stream>>>(W1, W2, Wself, WT);
    xbf_k <<<(Nn * 64 + 255) / 256, 256, 0, stream>>>(x, xb);
    hist_k <<<EB, 256, 0, stream>>>(ei, et, hist);
    scan1_k<<<196, 256, 0, stream>>>(hist, offs, bsum);
    scan2_k<<<1, 256, 0, stream>>>(bsum, bscan);
    scan3_k<<<196, 256, 0, stream>>>(offs, cur, bscan);
    fill_k <<<EB, 256, 0, stream>>>(ei, et, cur, ssrc);

    dim3 g1((Nn + 127) / 128, Rr);      // (391, 4)
    gemm1f_k<<<g1, 256, 0, stream>>>(xb, offs, ssrc, WT, b1, h, gsum, gsq);
    finalize_k<<<1, 512, 0, stream>>>(gsum, gsq, gamma, beta, coefA, coefC);
    gemm2f_k<<<(Nn + 127) / 128, 256, 0, stream>>>(
        xb, h, WT, bself, b2, coefA, coefC, out);
}

// Round 8
// 271.075 us; speedup vs baseline: 5.5751x; 1.1082x over previous
//
#include <hip/hip_runtime.h>

#define Nn 50000
#define Ee 600000
#define Rr 4
#define NSEG (Rr * Nn)
#define NBIN 200704             // 196*1024, padded for int4 scan
#define BN_EPS 1e-5f
#define ECAP 2048               // LDS edge-list cap per block

typedef __bf16 bfrag  __attribute__((ext_vector_type(8)));
typedef float  f32x4  __attribute__((ext_vector_type(4)));

__device__ __forceinline__ unsigned short f2b(float f) {
    union { float f; unsigned int u; } v; v.f = f;
    return (unsigned short)((v.u + 0x7FFFu + ((v.u >> 16) & 1u)) >> 16);
}
__device__ __forceinline__ float b2f(unsigned short u) {
    union { unsigned int u; float f; } v; v.u = ((unsigned int)u) << 16; return v.f;
}

// ---- prep: xbf (blocks 0..12499) | wt (12500..13075) | hist (13076..15419) ----
__global__ __launch_bounds__(256) void prep_k(
    const float* __restrict__ x, const float* __restrict__ W1,
    const float* __restrict__ W2, const float* __restrict__ Wself,
    const int* __restrict__ ei, const int* __restrict__ et,
    unsigned int* __restrict__ xb, unsigned short* __restrict__ WT,
    int* __restrict__ hist)
{
    int b = blockIdx.x;
    if (b < 12500) {                       // x -> packed bf16 (3.2M uints)
        int i = b * 256 + threadIdx.x;
        float2 v = ((const float2*)x)[i];
        xb[i] = ((unsigned int)f2b(v.y) << 16) | f2b(v.x);
    } else if (b < 13076) {                // weight transpose -> bf16 WT[mat][n][k]
        int idx = (b - 12500) * 256 + threadIdx.x;   // < 147456
        int mat = idx >> 14, rem = idx & 16383;
        int n = rem >> 7, k = rem & 127;
        const float* src = (mat < 4) ? (W1 + mat * 16384)
                         : (mat < 8) ? (W2 + (mat - 4) * 16384) : Wself;
        WT[idx] = f2b(src[k * 128 + n]);
    } else {                               // histogram over (r,dst) bins
        int e = (b - 13076) * 256 + threadIdx.x;
        if (e < Ee) atomicAdd(&hist[et[e] * Nn + ei[e]], 1);
    }
}

// ---- exclusive scan over NBIN ----
__global__ __launch_bounds__(256) void scan1_k(
    const int* __restrict__ hist, int* __restrict__ offs, int* __restrict__ bsum)
{
    int t = threadIdx.x, b = blockIdx.x;
    int base = b * 1024 + t * 4;
    int4 c = *(const int4*)(hist + base);
    int s = c.x + c.y + c.z + c.w;
    __shared__ int tmp[256];
    tmp[t] = s; __syncthreads();
    for (int off = 1; off < 256; off <<= 1) {
        int v = (t >= off) ? tmp[t - off] : 0;
        __syncthreads(); tmp[t] += v; __syncthreads();
    }
    int excl = tmp[t] - s;
    int4 o; o.x = excl; o.y = excl + c.x; o.z = o.y + c.y; o.w = o.z + c.z;
    *(int4*)(offs + base) = o;
    if (t == 255) bsum[b] = tmp[255];
}
__global__ void scan2_k(const int* __restrict__ bsum, int* __restrict__ bscan)
{
    int t = threadIdx.x;
    int s = (t < 196) ? bsum[t] : 0;
    __shared__ int tmp[256];
    tmp[t] = s; __syncthreads();
    for (int off = 1; off < 256; off <<= 1) {
        int v = (t >= off) ? tmp[t - off] : 0;
        __syncthreads(); tmp[t] += v; __syncthreads();
    }
    bscan[t] = tmp[t] - s;
}
__global__ __launch_bounds__(256) void scan3_k(
    int* __restrict__ offs, int* __restrict__ cur, const int* __restrict__ bscan)
{
    int t = threadIdx.x, b = blockIdx.x;
    int add = bscan[b];
    int base = b * 1024 + t * 4;
    int4 o = *(int4*)(offs + base);
    o.x += add; o.y += add; o.z += add; o.w += add;
    *(int4*)(offs + base) = o;
    *(int4*)(cur + base) = o;
}

// ---- bucket fill ----
__global__ __launch_bounds__(256) void fill_k(
    const int* __restrict__ ei, const int* __restrict__ et,
    int* __restrict__ cur, int* __restrict__ ssrc)
{
    int e = blockIdx.x * 256 + threadIdx.x;
    if (e >= Ee) return;
    int bin = et[e] * Nn + ei[e];
    int pos = atomicAdd(&cur[bin], 1);
    ssrc[pos] = ei[Ee + e];
}

// ---- FUSED: CSR gather-agg -> LDS -> @W1_r + b1 -> h1(bf16) + BN stats
//      128-row tiles, 512 threads, grid (391,4) ----
__global__ __launch_bounds__(512) void gemm1f_k(
    const unsigned int* __restrict__ xb, const int* __restrict__ offs,
    const int* __restrict__ ssrc, const unsigned short* __restrict__ WT,
    const float* __restrict__ b1, unsigned short* __restrict__ h,
    float* __restrict__ gsum, float* __restrict__ gsq)
{
    const int r  = blockIdx.y;
    const int n0 = blockIdx.x * 128;
    const int t  = threadIdx.x;

    __shared__ __attribute__((aligned(16))) __bf16 As[128][136];
    __shared__ __attribute__((aligned(16))) __bf16 Ws[128][136];
    __shared__ float s_sum[128], s_sq[128];
    __shared__ int s_off[129];
    __shared__ int s_edge[ECAP];

    if (t < 128) { s_sum[t] = 0.f; s_sq[t] = 0.f; }
    const int rows = (Nn - n0 < 128) ? (Nn - n0) : 128;
    if (t <= rows) s_off[t] = offs[r * Nn + n0 + t];
    __syncthreads();

    const int ebeg = s_off[0];
    const int ecnt = s_off[rows] - ebeg;
    const bool inl = (ecnt <= ECAP);
    if (inl) for (int i = t; i < ecnt; i += 512) s_edge[i] = ssrc[ebeg + i];
    // stage W1_r
    {
        const unsigned short* Wr = WT + r * 16384;
        for (int i = t; i < 2048; i += 512) {
            int n = i >> 4, kc = (i & 15) << 3;
            *(uint4*)&Ws[n][kc] = *(const uint4*)(Wr + n * 128 + kc);
        }
    }
    __syncthreads();

    // gather h0 = x[dst] + sum x[src]; 4 thr/row, 16 uints each
    {
        const int row = t >> 2, q = t & 3, gm = n0 + row;
        float acc[32];
        if (gm < Nn) {
            const uint4* xr = (const uint4*)(xb + (size_t)gm * 64 + q * 16);
            uint4 u0 = xr[0], u1 = xr[1], u2 = xr[2], u3 = xr[3];
            unsigned int us[16] = {u0.x,u0.y,u0.z,u0.w, u1.x,u1.y,u1.z,u1.w,
                                   u2.x,u2.y,u2.z,u2.w, u3.x,u3.y,u3.z,u3.w};
#pragma unroll
            for (int j = 0; j < 16; ++j) {
                acc[2*j]   = b2f((unsigned short)(us[j] & 0xFFFF));
                acc[2*j+1] = b2f((unsigned short)(us[j] >> 16));
            }
            int jb = s_off[row] - ebeg, je = s_off[row + 1] - ebeg;
            for (int j = jb; j < je; ++j) {
                int src = inl ? s_edge[j] : ssrc[ebeg + j];
                const uint4* sr = (const uint4*)(xb + (size_t)src * 64 + q * 16);
                uint4 v0 = sr[0], v1 = sr[1], v2 = sr[2], v3 = sr[3];
                unsigned int vs[16] = {v0.x,v0.y,v0.z,v0.w, v1.x,v1.y,v1.z,v1.w,
                                       v2.x,v2.y,v2.z,v2.w, v3.x,v3.y,v3.z,v3.w};
#pragma unroll
                for (int jj = 0; jj < 16; ++jj) {
                    acc[2*jj]   += b2f((unsigned short)(vs[jj] & 0xFFFF));
                    acc[2*jj+1] += b2f((unsigned short)(vs[jj] >> 16));
                }
            }
        } else {
#pragma unroll
            for (int j = 0; j < 32; ++j) acc[j] = 0.f;
        }
        unsigned int pk[16];
#pragma unroll
        for (int j = 0; j < 16; ++j)
            pk[j] = ((unsigned int)f2b(acc[2*j+1]) << 16) | f2b(acc[2*j]);
        uint4* dst = (uint4*)&As[row][q * 32];
        dst[0] = make_uint4(pk[0],  pk[1],  pk[2],  pk[3]);
        dst[1] = make_uint4(pk[4],  pk[5],  pk[6],  pk[7]);
        dst[2] = make_uint4(pk[8],  pk[9],  pk[10], pk[11]);
        dst[3] = make_uint4(pk[12], pk[13], pk[14], pk[15]);
    }
    __syncthreads();

    // MFMA: wave w -> rows [w*16, w*16+16)
    const int w = t >> 6, l = t & 63, ln = l & 15, quad = l >> 4;
    f32x4 acc2[8];
#pragma unroll
    for (int c = 0; c < 8; ++c) acc2[c] = (f32x4){0.f,0.f,0.f,0.f};
#pragma unroll
    for (int kk = 0; kk < 4; ++kk) {
        int ks = kk * 32 + quad * 8;
        bfrag a = *(const bfrag*)&As[w * 16 + ln][ks];
#pragma unroll
        for (int c = 0; c < 8; ++c) {
            bfrag b = *(const bfrag*)&Ws[c * 16 + ln][ks];
            acc2[c] = __builtin_amdgcn_mfma_f32_16x16x32_bf16(a, b, acc2[c], 0, 0, 0);
        }
    }
    __syncthreads();

    // Epilogue: +bias, BN stats (fp32), bf16 back into As
#pragma unroll
    for (int c = 0; c < 8; ++c) {
        int col = c * 16 + ln;
        float bias = b1[r * 128 + col];
        float ps = 0.f, pq = 0.f;
#pragma unroll
        for (int reg = 0; reg < 4; ++reg) {
            int lrow = w * 16 + quad * 4 + reg;
            float v = acc2[c][reg] + bias;
            As[lrow][col] = (__bf16)v;
            if (n0 + lrow < Nn) { ps += v; pq += v * v; }
        }
        ps += __shfl_xor(ps, 16); pq += __shfl_xor(pq, 16);
        ps += __shfl_xor(ps, 32); pq += __shfl_xor(pq, 32);
        if (quad == 0) { atomicAdd(&s_sum[col], ps); atomicAdd(&s_sq[col], pq); }
    }
    __syncthreads();

    unsigned short* hr = h + (size_t)r * Nn * 128;
    for (int i = t; i < 2048; i += 512) {
        int m = i >> 4, kc = (i & 15) << 3;
        int gm = n0 + m;
        if (gm < Nn) *(uint4*)(hr + (size_t)gm * 128 + kc) = *(const uint4*)&As[m][kc];
    }
    if (t < 128) {
        atomicAdd(&gsum[r * 128 + t], s_sum[t]);
        atomicAdd(&gsq[r * 128 + t],  s_sq[t]);
    }
}

// ---- BN coefs ----
__global__ void finalize_k(
    const float* __restrict__ gsum, const float* __restrict__ gsq,
    const float* __restrict__ gamma, const float* __restrict__ beta,
    float* __restrict__ coefA, float* __restrict__ coefC)
{
    int i = threadIdx.x;   // 512
    float mean = gsum[i] * (1.0f / Nn);
    float var  = gsq[i] * (1.0f / Nn) - mean * mean;
    float a    = gamma[i] * rsqrtf(fmaxf(var, 0.f) + BN_EPS);
    coefA[i] = a;
    coefC[i] = beta[i] - mean * a;
}

// ---- out = x@W_self + sum_r relu(a*h1+c)@W2_r + biases; 128-row tiles, 512 thr ----
__global__ __launch_bounds__(512) void gemm2f_k(
    const unsigned int* __restrict__ xb,
    const unsigned short* __restrict__ h,
    const unsigned short* __restrict__ WT,
    const float* __restrict__ bself, const float* __restrict__ b2,
    const float* __restrict__ coefA, const float* __restrict__ coefC,
    float* __restrict__ out)
{
    const int n0 = blockIdx.x * 128;
    const int t  = threadIdx.x;
    __shared__ __attribute__((aligned(16))) __bf16 As[128][136];
    __shared__ __attribute__((aligned(16))) __bf16 Ws[128][136];

    const int w = t >> 6, l = t & 63, ln = l & 15, quad = l >> 4;
    f32x4 acc2[8];
#pragma unroll
    for (int c = 0; c < 8; ++c) acc2[c] = (f32x4){0.f,0.f,0.f,0.f};

    for (int rr = 0; rr < 5; ++rr) {
        const unsigned short* Wr = WT + (rr < 4 ? (4 + rr) : 8) * 16384;
        for (int i = t; i < 2048; i += 512) {
            int n = i >> 4, kc = (i & 15) << 3;
            *(uint4*)&Ws[n][kc] = *(const uint4*)(Wr + n * 128 + kc);
        }
        if (rr < 4) {
            const unsigned short* hrp = h + (size_t)rr * Nn * 128;
            const float* cA = coefA + rr * 128;
            const float* cC = coefC + rr * 128;
            for (int i = t; i < 2048; i += 512) {     // 8 bf16 per chunk
                int m = i >> 4, kc = (i & 15) << 3;
                int gm = n0 + m;
                uint4 hv = make_uint4(0,0,0,0);
                if (gm < Nn) hv = *(const uint4*)(hrp + (size_t)gm * 128 + kc);
                unsigned int hu[4] = {hv.x, hv.y, hv.z, hv.w};
                unsigned int pk[4];
#pragma unroll
                for (int j = 0; j < 4; ++j) {
                    float v0 = fmaxf(cA[kc + 2*j]     * b2f((unsigned short)(hu[j] & 0xFFFF)) + cC[kc + 2*j],     0.f);
                    float v1 = fmaxf(cA[kc + 2*j + 1] * b2f((unsigned short)(hu[j] >> 16))    + cC[kc + 2*j + 1], 0.f);
                    pk[j] = ((unsigned int)f2b(v1) << 16) | f2b(v0);
                }
                *(uint4*)&As[m][kc] = make_uint4(pk[0], pk[1], pk[2], pk[3]);
            }
        } else {
            for (int i = t; i < 2048; i += 512) {
                int m = i >> 4, kc = (i & 15) << 3;
                int gm = n0 + m;
                uint4 v = make_uint4(0, 0, 0, 0);
                if (gm < Nn) v = *(const uint4*)(xb + (size_t)gm * 64 + (kc >> 1));
                *(uint4*)&As[m][kc] = v;
            }
        }
        __syncthreads();
#pragma unroll
        for (int kk = 0; kk < 4; ++kk) {
            int ks = kk * 32 + quad * 8;
            bfrag a = *(const bfrag*)&As[w * 16 + ln][ks];
#pragma unroll
            for (int c = 0; c < 8; ++c) {
                bfrag b = *(const bfrag*)&Ws[c * 16 + ln][ks];
                acc2[c] = __builtin_amdgcn_mfma_f32_16x16x32_bf16(a, b, acc2[c], 0, 0, 0);
            }
        }
        __syncthreads();
    }

    // Epilogue: fp32 transpose through Ws, coalesced stores; 2 passes of 64 rows
    float bias[8];
#pragma unroll
    for (int c = 0; c < 8; ++c) {
        int col = c * 16 + ln;
        bias[c] = bself[col] + b2[col] + b2[128 + col] + b2[256 + col] + b2[384 + col];
    }
    float* fws = (float*)Ws;
    for (int p = 0; p < 2; ++p) {
        if ((w >> 2) == p) {
#pragma unroll
            for (int c = 0; c < 8; ++c) {
                int lrow = (w & 3) * 16 + quad * 4;
                int col  = c * 16 + ln;
#pragma unroll
                for (int reg = 0; reg < 4; ++reg)
                    fws[(lrow + reg) * 132 + col] = acc2[c][reg] + bias[c];
            }
        }
        __syncthreads();
        for (int i = t; i < 2048; i += 512) {
            int m = i >> 5, kc = (i & 31) << 2;
            int gm = n0 + p * 64 + m;
            if (gm < Nn)
                *(float4*)(out + (size_t)gm * 128 + kc) = *(const float4*)&fws[m * 132 + kc];
        }
        __syncthreads();
    }
}

extern "C" void kernel_launch(void* const* d_in, const int* in_sizes, int n_in,
                              void* d_out, int out_size, void* d_ws, size_t ws_size,
                              hipStream_t stream) {
    const float* x     = (const float*)d_in[0];
    const int*   ei    = (const int*)d_in[1];
    const int*   et    = (const int*)d_in[2];
    const float* Wself = (const float*)d_in[3];
    const float* bself = (const float*)d_in[4];
    const float* W1    = (const float*)d_in[5];
    const float* b1    = (const float*)d_in[6];
    const float* gamma = (const float*)d_in[7];
    const float* beta  = (const float*)d_in[8];
    const float* W2    = (const float*)d_in[9];
    const float* b2    = (const float*)d_in[10];
    float* out = (float*)d_out;

    char* ws = (char*)d_ws;
    int*   hist  = (int*)(ws + 0);                      // 802,816
    float* gsum  = (float*)(ws + 802816);               // 2048
    float* gsq   = (float*)(ws + 804864);               // 2048
    float* coefA = (float*)(ws + 806912);               // 2048
    float* coefC = (float*)(ws + 808960);               // 2048
    int*   bsum  = (int*)(ws + 811008);                 // 1024
    int*   bscan = (int*)(ws + 812032);                 // 1024
    int*   offs  = (int*)(ws + 813056);                 // 802,816
    int*   cur   = (int*)(ws + 1615872);                // 802,816
    int*   ssrc  = (int*)(ws + 2418688);                // 2,400,000
    unsigned short* h  = (unsigned short*)(ws + 4818688);   // 51,200,000
    unsigned int*   xb = (unsigned int*)(ws + 56018688);    // 12,800,000
    unsigned short* WT = (unsigned short*)(ws + 68818688);  // 294,912

    (void)hipMemsetAsync(ws, 0, 806912, stream);   // hist + gsum + gsq

    const int EB = (Ee + 255) / 256;                    // 2344
    prep_k <<<12500 + 576 + EB, 256, 0, stream>>>(x, W1, W2, Wself, ei, et, xb, WT, hist);
    scan1_k<<<196, 256, 0, stream>>>(hist, offs, bsum);
    scan2_k<<<1, 256, 0, stream>>>(bsum, bscan);
    scan3_k<<<196, 256, 0, stream>>>(offs, cur, bscan);
    fill_k <<<EB, 256, 0, stream>>>(ei, et, cur, ssrc);

    dim3 g1((Nn + 127) / 128, Rr);      // (391, 4)
    gemm1f_k<<<g1, 512, 0, stream>>>(xb, offs, ssrc, WT, b1, h, gsum, gsq);
    finalize_k<<<1, 512, 0, stream>>>(gsum, gsq, gamma, beta, coefA, coefC);
    gemm2f_k<<<(Nn + 127) / 128, 512, 0, stream>>>(
        xb, h, WT, bself, b2, coefA, coefC, out);
}